// Round 7
// baseline (156.970 us; speedup 1.0000x reference)
//
#include <hip/hip_runtime.h>

// Problem dims
constexpr int Bb = 64;     // batch
constexpr int Tt = 256;    // timesteps
constexpr int Dd = 512;    // input dim (K)
constexpr int Hh = 1024;   // hidden (N)
constexpr int Mm = Bb * Tt;  // 16384 GEMM rows

typedef _Float16 half8 __attribute__((ext_vector_type(8)));
typedef _Float16 half4v __attribute__((ext_vector_type(4)));
typedef float floatx16 __attribute__((ext_vector_type(16)));

#define GPTR(x) ((const __attribute__((address_space(1))) void*)(x))
#define LPTR(x) ((__attribute__((address_space(3))) void*)(x))

// ---------------------------------------------------------------------------
// Kernel 1 (W-ONLY): fp32 -> f16 hi/lo split, chunk-transposed.
// R6 proved: removing the x round-trip cut non-gemm time 80->61us (convert_t
// was ~20us; ~60us is fixed harness overhead). W is only 2MB -> ~3us here.
// Also initializes out[b] = b_out (out is re-poisoned before every launch).
// ---------------------------------------------------------------------------
__global__ __launch_bounds__(256) void convert_w(const float* __restrict__ Win,
                                                 _Float16* __restrict__ wh,
                                                 _Float16* __restrict__ wl,
                                                 const float* __restrict__ bout,
                                                 float* __restrict__ out) {
    __shared__ _Float16 lh[64 * 72];
    __shared__ _Float16 ll[64 * 72];
    const int tid = threadIdx.x;
    const int k0 = blockIdx.x * 64;
    const int m0 = blockIdx.y * 64;
    const int nrows = Hh;

    if (blockIdx.x == 0 && blockIdx.y == 0 && tid < Bb) out[tid] = bout[0];

#pragma unroll
    for (int i = 0; i < 4; ++i) {
        const int lin = tid + i * 256;
        const int row = lin >> 4;
        const int c4 = (lin & 15) * 4;
        const float4 v = *(const float4*)(Win + (size_t)(m0 + row) * Dd + k0 + c4);
        const float va[4] = {v.x, v.y, v.z, v.w};
        half4v h, l;
#pragma unroll
        for (int q = 0; q < 4; ++q) {
            const _Float16 hi = (_Float16)va[q];
            h[q] = hi;
            l[q] = (_Float16)((va[q] - (float)hi) * 4096.0f);
        }
        *(half4v*)&lh[row * 72 + c4] = h;
        *(half4v*)&ll[row * 72 + c4] = l;
    }
    __syncthreads();
#pragma unroll
    for (int i = 0; i < 2; ++i) {
        const int lin = tid + i * 256;
        const int kc = lin >> 6;   // 0..7
        const int mm = lin & 63;
        const half8 h = *(const half8*)&lh[mm * 72 + kc * 8];
        const half8 l = *(const half8*)&ll[mm * 72 + kc * 8];
        const size_t g = (size_t)(k0 / 8 + kc) * nrows + m0 + mm;
        *(half8*)(wh + g * 8) = h;
        *(half8*)(wl + g * 8) = l;
    }
}

// ---------------------------------------------------------------------------
// Kernel 2: FUSED fp32-split MFMA GEMM + ALIF scan.
// R7: R6's fused conversion regressed gemm 64->95us because CONVA was one
// ~100-op VALU lump at the MFMA cluster head -- both barrier-synced waves
// convert while the MFMA pipe drains. Fix: split the conversion and hide it
// INSIDE the cluster. MFMA group 2 (ah*bl) does not need al, so:
//   CONVA_H (cvt+pack, ~50 ops)  -> groups 1+2 (8 MFMA, 256 pipe-cyc)
//   CONVA_L (~90 ops) issues while groups 1+2 drain (fits the 256cy shadow)
//   -> group 3 (al*bh).
// sched_barrier(0) fences pin CONVA_L between group 2 and group 3 (the
// compiler would otherwise re-lump it). Per-accumulator FP order unchanged
// (bit-exact vs R5/R6).
// Kept: A fp32 direct loads 1-ahead/2-slot, B-fragment register dbuf,
// counted s_waitcnt vmcnt(4) + raw s_barrier per SS, setprio, XCD swizzle,
// R1 epilogue. B (wh/wl): global_load_lds into 32KB dbuf LDS.
// Tile M=256 x N=64, 4 waves; reg-capped 2 waves/SIMD (128 AGPR + ~116 VGPR).
// ---------------------------------------------------------------------------
__global__ __launch_bounds__(256, 2) void gemm_fused(const float* __restrict__ x,
                                                     const _Float16* __restrict__ wh,
                                                     const _Float16* __restrict__ wl,
                                                     const float* __restrict__ bin,
                                                     const float* __restrict__ Wout,
                                                     float* __restrict__ out) {
    __shared__ float ldsS[16384];  // 64KB: K-loop uses first 32KB as B dbuf;
                                   // epilogue reuses all 64KB as scanbuf.
    _Float16* ldsB = (_Float16*)ldsS;  // [buf][arr][4096 halves]

    const int tid = threadIdx.x;
    // XCD swizzle: j = id%8 = XCD slot; batch b ≡ j (mod 8); n-tile fast.
    const int id = blockIdx.x;          // 0..1023
    const int j  = id & 7;
    const int q  = id >> 3;             // 0..127
    const int nt = q & 15;              // n-tile 0..15 (64 cols each)
    const int b  = (q >> 4) * 8 + j;    // batch 0..63
    const int m0 = b * Tt;              // = b*256
    const int n0 = nt * 64;

    const int lane = tid & 63;
    const int wave = tid >> 6;          // 0..3, owns rows [64w, 64w+64)
    const int lr = lane & 31;
    const int lk = lane >> 5;

    floatx16 acc[2][2], accx[2][2];
#pragma unroll
    for (int mi = 0; mi < 2; ++mi)
#pragma unroll
        for (int ni = 0; ni < 2; ++ni)
#pragma unroll
            for (int r = 0; r < 16; ++r) { acc[mi][ni][r] = 0.0f; accx[mi][ni][r] = 0.0f; }

    // --- B staging: super-stage SS covers k-chunks [SS*8, SS*8+8) (64 k).
#define STAGE_B(buf, SS)                                                             \
    do {                                                                             \
        _Pragma("unroll")                                                            \
        for (int i_ = 0; i_ < 2; ++i_) {                                             \
            const int c_ = tid + i_ * 256;                                           \
            const int kc_ = c_ >> 6;                                                 \
            const int col_ = c_ & 63;                                                \
            const size_t g_ = ((size_t)((SS) * 8 + kc_) * Hh + n0 + col_) * 8;       \
            __builtin_amdgcn_global_load_lds(GPTR(wh + g_), LPTR(&ldsB[((buf) * 2 + 0) * 4096 + c_ * 8]), 16, 0, 0); \
            __builtin_amdgcn_global_load_lds(GPTR(wl + g_), LPTR(&ldsB[((buf) * 2 + 1) * 4096 + c_ * 8]), 16, 0, 0); \
        }                                                                            \
    } while (0)

    // --- A fp32 direct loads (wave-private rows), 1-ahead 2-slot prefetch ---
    const float* xbase = x + (size_t)(m0 + wave * 64 + lr) * Dd;
    float4 fpre[2][2][2];  // [slot][mi][half]; slot = hs & 1 (compile-time)
#define LOAD_AF(slot, hs)                                                            \
    do {                                                                             \
        const int kof_ = ((hs) * 2 + lk) * 8;                                        \
        fpre[slot][0][0] = *(const float4*)(xbase + kof_);                           \
        fpre[slot][0][1] = *(const float4*)(xbase + kof_ + 4);                       \
        fpre[slot][1][0] = *(const float4*)(xbase + (size_t)32 * Dd + kof_);         \
        fpre[slot][1][1] = *(const float4*)(xbase + (size_t)32 * Dd + kof_ + 4);     \
    } while (0)

    // In-register hi/lo split, SPLIT into H and L phases. Same fp32 ops as
    // convert_t -> MFMA inputs bit-identical to the precomputed-xh/xl path.
    half8 ah_[2], al_[2];
#define CONVA_H(slot_)                                                               \
    do {                                                                             \
        _Pragma("unroll")                                                            \
        for (int mi_ = 0; mi_ < 2; ++mi_) {                                          \
            const float va_[8] = {fpre[slot_][mi_][0].x, fpre[slot_][mi_][0].y,      \
                                  fpre[slot_][mi_][0].z, fpre[slot_][mi_][0].w,      \
                                  fpre[slot_][mi_][1].x, fpre[slot_][mi_][1].y,      \
                                  fpre[slot_][mi_][1].z, fpre[slot_][mi_][1].w};     \
            _Pragma("unroll")                                                        \
            for (int e_ = 0; e_ < 8; ++e_) ah_[mi_][e_] = (_Float16)va_[e_];         \
        }                                                                            \
    } while (0)
#define CONVA_L(slot_)                                                               \
    do {                                                                             \
        _Pragma("unroll")                                                            \
        for (int mi_ = 0; mi_ < 2; ++mi_) {                                          \
            const float va_[8] = {fpre[slot_][mi_][0].x, fpre[slot_][mi_][0].y,      \
                                  fpre[slot_][mi_][0].z, fpre[slot_][mi_][0].w,      \
                                  fpre[slot_][mi_][1].x, fpre[slot_][mi_][1].y,      \
                                  fpre[slot_][mi_][1].z, fpre[slot_][mi_][1].w};     \
            _Pragma("unroll")                                                        \
            for (int e_ = 0; e_ < 8; ++e_) {                                         \
                const float h32_ = (float)ah_[mi_][e_];                              \
                al_[mi_][e_] = (_Float16)((va_[e_] - h32_) * 4096.0f);               \
            }                                                                        \
        }                                                                            \
    } while (0)

    // --- B fragments, explicit 2-deep register double-buffer ---
    half8 bfh[2][2], bfl[2][2];  // [rot][ni]; rot = qq & 1 (compile-time)
#define LOAD_BF(rot_, qq_, cur_)                                                     \
    do {                                                                             \
        _Pragma("unroll")                                                            \
        for (int ni_ = 0; ni_ < 2; ++ni_) {                                          \
            const int ci_ = ((qq_) * 2 + lk) * 64 + ni_ * 32 + lr;                   \
            bfh[rot_][ni_] = *(const half8*)&ldsB[((cur_) * 2 + 0) * 4096 + ci_ * 8];\
            bfl[rot_][ni_] = *(const half8*)&ldsB[((cur_) * 2 + 1) * 4096 + ci_ * 8];\
        }                                                                            \
    } while (0)

#define SB0() __builtin_amdgcn_sched_barrier(0)
#define WAITVM4() asm volatile("s_waitcnt vmcnt(4)" ::: "memory")
#define CFENCE() asm volatile("" ::: "memory")

    // Prologue: stage B(0) (4 glds), prefetch A chunk 0 (4 loads).
    // vmcnt(4) retires the staging glds, keeps the 4 A-loads in flight.
    STAGE_B(0, 0);
    SB0();
    LOAD_AF(0, 0);
    SB0();
    WAITVM4();
    __builtin_amdgcn_s_barrier();
    CFENCE();

    for (int SS = 0; SS < 8; ++SS) {
        if (SS < 7) { STAGE_B((SS + 1) & 1, SS + 1); SB0(); }
        const int cur = SS & 1;
        LOAD_BF(0, 0, cur);  // prime the B-fragment pipeline for qq=0
#pragma unroll
        for (int qq = 0; qq < 4; ++qq) {
            const int hs = SS * 4 + qq;
            const int rot = qq & 1;
            const int slot = qq & 1;       // == hs & 1 (SS*4 even)
            // Pipeline: next-qq B-frag ds_reads + next-hs A fp32 loads issue
            // first; their latencies hide under this qq's conv+MFMAs.
            if (qq < 3) LOAD_BF(rot ^ 1, qq + 1, cur);
            if (hs + 1 < 32) LOAD_AF(slot ^ 1, hs + 1);
            SB0();   // loads stay above the conversion/MFMA region

            CONVA_H(slot);  // ah only (~50 ops) -- group 3's al comes later

            __builtin_amdgcn_s_setprio(1);
#pragma unroll
            for (int mi = 0; mi < 2; ++mi)
#pragma unroll
                for (int ni = 0; ni < 2; ++ni)
                    acc[mi][ni]  = __builtin_amdgcn_mfma_f32_32x32x16_f16(ah_[mi], bfh[rot][ni], acc[mi][ni], 0, 0, 0);
#pragma unroll
            for (int mi = 0; mi < 2; ++mi)
#pragma unroll
                for (int ni = 0; ni < 2; ++ni)
                    accx[mi][ni] = __builtin_amdgcn_mfma_f32_32x32x16_f16(ah_[mi], bfl[rot][ni], accx[mi][ni], 0, 0, 0);
            __builtin_amdgcn_s_setprio(0);
            SB0();          // pin: CONVA_L stays BELOW groups 1+2 ...
            CONVA_L(slot);  // ~90 ops issue while the 8 MFMAs above drain
            SB0();          // ... and ABOVE group 3
            __builtin_amdgcn_s_setprio(1);
#pragma unroll
            for (int mi = 0; mi < 2; ++mi)
#pragma unroll
                for (int ni = 0; ni < 2; ++ni)
                    accx[mi][ni] = __builtin_amdgcn_mfma_f32_32x32x16_f16(al_[mi], bfh[rot][ni], accx[mi][ni], 0, 0, 0);
            __builtin_amdgcn_s_setprio(0);
        }
        if (SS < 7) {
            SB0();           // pin: staging glds(SS+1) issued before this SS's A-loads
            WAITVM4();       // retire 4 staging glds; keep the 4 newest A-loads flying
            __builtin_amdgcn_s_barrier();
            CFENCE();        // no LDS read hoists above the barrier
        }
    }
#undef STAGE_B
#undef LOAD_AF
#undef CONVA_H
#undef CONVA_L
#undef LOAD_BF

    // ---------------- fused ALIF scan epilogue ----------------
    __syncthreads();  // full drain once; reuse ldsS as 2 scan buffers
    float* scanbuf = ldsS;  // buffer p at offset p*8192 floats (stride 32)

#pragma unroll
    for (int p = 0; p < 2; ++p) {
        const float bv = bin[n0 + p * 32 + lr];
        // C/D layout (32x32): col = lane&31, row = (r&3) + 8*(r>>2) + 4*lk
#pragma unroll
        for (int mi = 0; mi < 2; ++mi)
#pragma unroll
            for (int r = 0; r < 16; ++r) {
                const int row = (r & 3) + 8 * (r >> 2) + 4 * lk;
                const int t = wave * 64 + mi * 32 + row;   // m_local == timestep
                scanbuf[p * 8192 + t * 32 + lr] =
                    acc[mi][p][r] + accx[mi][p][r] * (1.0f / 4096.0f) + bv;
            }
    }
    __syncthreads();

    // Wave 0 scans all 64 h (lane = h - n0); waves 1-3 exit immediately.
    if (wave == 0) {
        const float* sb = scanbuf + (lane >> 5) * 8192 + (lane & 31);
        const float wout = Wout[n0 + lane];  // hoisted: latency hides under scan
        float mem = 0.0f, adapt = 0.0f, cnt = 0.0f;

        float buf[16];
#pragma unroll
        for (int jj = 0; jj < 16; ++jj) buf[jj] = sb[jj * 32];

        for (int t0 = 0; t0 < Tt; t0 += 16) {
            float cur[16];
#pragma unroll
            for (int jj = 0; jj < 16; ++jj) cur[jj] = buf[jj];
            if (t0 + 16 < Tt) {
#pragma unroll
                for (int jj = 0; jj < 16; ++jj) buf[jj] = sb[(t0 + 16 + jj) * 32];
            }
#pragma unroll
            for (int jj = 0; jj < 16; ++jj) {
                mem = 0.9f * mem + cur[jj] - adapt;
                const float spk = (mem > 0.0f) ? 1.0f : 0.0f;
                adapt += 0.1f * spk;
                mem -= spk;
                cnt += spk;
            }
        }
        float val = cnt * wout * (1.0f / (float)Tt);
#pragma unroll
        for (int off = 32; off > 0; off >>= 1) val += __shfl_down(val, off, 64);
        if (lane == 0) atomicAdd(&out[b], val);
    }
}

// ---------------------------------------------------------------------------
// Fallback fp32 SIMT GEMM + scan (proven) in case ws is too small.
// ---------------------------------------------------------------------------
#define BK 16
#define BMP 132
__global__ __launch_bounds__(256) void gemm_pre(const float* __restrict__ x,
                                                const float* __restrict__ Win,
                                                const float* __restrict__ bin,
                                                float* __restrict__ pre) {
    __shared__ float As[BK][BMP];
    __shared__ float Bs[BK][BMP];
    const int tid = threadIdx.x;
    const int m0 = blockIdx.y * 128;
    const int n0 = blockIdx.x * 128;
    const int tx = tid & 15;
    const int ty = tid >> 4;
    float acc[8][8];
#pragma unroll
    for (int i = 0; i < 8; ++i)
#pragma unroll
        for (int jj = 0; jj < 8; ++jj) acc[i][jj] = 0.0f;
    const float* Aptr = x + (size_t)m0 * Dd;
    const float* Bptr = Win + (size_t)n0 * Dd;
    for (int k0 = 0; k0 < Dd; k0 += BK) {
#pragma unroll
        for (int i = 0; i < 2; ++i) {
            const int lin = tid + i * 256;
            const int row = lin >> 2;
            const int kq = (lin & 3) << 2;
            const float4 av = *(const float4*)(Aptr + (size_t)row * Dd + k0 + kq);
            const float4 bv = *(const float4*)(Bptr + (size_t)row * Dd + k0 + kq);
            As[kq + 0][row] = av.x; As[kq + 1][row] = av.y;
            As[kq + 2][row] = av.z; As[kq + 3][row] = av.w;
            Bs[kq + 0][row] = bv.x; Bs[kq + 1][row] = bv.y;
            Bs[kq + 2][row] = bv.z; Bs[kq + 3][row] = bv.w;
        }
        __syncthreads();
#pragma unroll
        for (int kk = 0; kk < BK; ++kk) {
            const float4 a0 = *(const float4*)&As[kk][ty * 4];
            const float4 a1 = *(const float4*)&As[kk][ty * 4 + 64];
            const float4 b0 = *(const float4*)&Bs[kk][tx * 4];
            const float4 b1 = *(const float4*)&Bs[kk][tx * 4 + 64];
            const float a[8] = {a0.x, a0.y, a0.z, a0.w, a1.x, a1.y, a1.z, a1.w};
            const float b[8] = {b0.x, b0.y, b0.z, b0.w, b1.x, b1.y, b1.z, b1.w};
#pragma unroll
            for (int i = 0; i < 8; ++i)
#pragma unroll
                for (int jj = 0; jj < 8; ++jj) acc[i][jj] += a[i] * b[jj];
        }
        __syncthreads();
    }
#pragma unroll
    for (int i = 0; i < 8; ++i) {
        const int m = m0 + ((i < 4) ? (ty * 4 + i) : (64 + ty * 4 + i - 4));
#pragma unroll
        for (int half = 0; half < 2; ++half) {
            const int n = n0 + tx * 4 + half * 64;
            float4 v;
            v.x = acc[i][half * 4 + 0] + bin[n + 0];
            v.y = acc[i][half * 4 + 1] + bin[n + 1];
            v.z = acc[i][half * 4 + 2] + bin[n + 2];
            v.w = acc[i][half * 4 + 3] + bin[n + 3];
            *(float4*)(pre + (size_t)m * Hh + n) = v;
        }
    }
}

__global__ __launch_bounds__(64) void init_out(const float* __restrict__ bout,
                                               float* __restrict__ out) {
    out[threadIdx.x] = bout[0];
}

__global__ __launch_bounds__(64) void alif_scan(const float* __restrict__ pre,
                                                const float* __restrict__ Wout,
                                                float* __restrict__ out) {
    const int h = blockIdx.x * 64 + threadIdx.x;
    const int b = blockIdx.y;
    const float* p = pre + (size_t)b * Tt * Hh + h;

    float buf[32];
#pragma unroll
    for (int jj = 0; jj < 32; ++jj) buf[jj] = p[(size_t)jj * Hh];

    float mem = 0.0f, adapt = 0.0f, cnt = 0.0f;
    for (int t0 = 0; t0 < Tt; t0 += 32) {
        float cur[32];
#pragma unroll
        for (int jj = 0; jj < 32; ++jj) cur[jj] = buf[jj];
        if (t0 + 32 < Tt) {
#pragma unroll
            for (int jj = 0; jj < 32; ++jj) buf[jj] = p[(size_t)(t0 + 32 + jj) * Hh];
        }
#pragma unroll
        for (int jj = 0; jj < 32; ++jj) {
            mem = 0.9f * mem + cur[jj] - adapt;
            const float spk = (mem > 0.0f) ? 1.0f : 0.0f;
            adapt += 0.1f * spk;
            mem -= spk;
            cnt += spk;
        }
    }

    float val = cnt * Wout[h] * (1.0f / (float)Tt);
#pragma unroll
    for (int off = 32; off > 0; off >>= 1) val += __shfl_down(val, off, 64);
    if (threadIdx.x == 0) atomicAdd(&out[b], val);
}

extern "C" void kernel_launch(void* const* d_in, const int* in_sizes, int n_in,
                              void* d_out, int out_size, void* d_ws, size_t ws_size,
                              hipStream_t stream) {
    const float* x    = (const float*)d_in[0];
    const float* Win  = (const float*)d_in[1];
    const float* bin  = (const float*)d_in[2];
    const float* Wout = (const float*)d_in[3];
    const float* bout = (const float*)d_in[4];
    float* out = (float*)d_out;

    const size_t wh_bytes = (size_t)Hh * Dd * 2;   // 1 MiB
    const size_t need = 2 * wh_bytes + 4096;

    if (ws_size >= need) {
        char* base = (char*)d_ws;
        _Float16* wh = (_Float16*)base;
        _Float16* wl = (_Float16*)(base + wh_bytes);

        // W: 16 row-tiles of 64, 8 k-tiles of 64. x conversion is fused into
        // gemm_fused's A-path (reads fp32 directly, splits in-register).
        convert_w<<<dim3(8, 16), 256, 0, stream>>>(Win, wh, wl, bout, out);

        gemm_fused<<<1024, 256, 0, stream>>>(x, wh, wl, bin, Wout, out);
    } else {
        float* pre = (float*)d_ws;  // needs 64 MiB
        init_out<<<1, 64, 0, stream>>>(bout, out);
        dim3 g1(Hh / 128, Mm / 128);
        gemm_pre<<<g1, 256, 0, stream>>>(x, Win, bin, pre);
        alif_scan<<<dim3(Hh / 64, Bb), 64, 0, stream>>>(pre, Wout, out);
    }
}

// Round 8
// 156.005 us; speedup vs baseline: 1.0062x; 1.0062x over previous
//
#include <hip/hip_runtime.h>

// Problem dims
constexpr int Bb = 64;     // batch
constexpr int Tt = 256;    // timesteps
constexpr int Dd = 512;    // input dim (K)
constexpr int Hh = 1024;   // hidden (N)
constexpr int Mm = Bb * Tt;  // 16384 GEMM rows

typedef _Float16 half8 __attribute__((ext_vector_type(8)));
typedef _Float16 half4v __attribute__((ext_vector_type(4)));
typedef float floatx16 __attribute__((ext_vector_type(16)));

#define GPTR(x) ((const __attribute__((address_space(1))) void*)(x))
#define LPTR(x) ((__attribute__((address_space(3))) void*)(x))

// ---------------------------------------------------------------------------
// Kernel 1: fp32 -> f16 hi/lo split, chunk-transposed (R9-proven, restored).
// R6/R7 lesson: fusing the split into the GEMM makes it VALU-bound (per-SIMD
// conversion issue 400cy vs 192cy MFMA work per hs) -- precompute wins even
// with the extra 64MB round-trip. Chunk g = kc*nrows + row holds
// src[row][kc*8..+8) as 8 halves. Also initializes out[b] = b_out.
// ---------------------------------------------------------------------------
__global__ __launch_bounds__(256) void convert_t(const float* __restrict__ x,
                                                 const float* __restrict__ Win,
                                                 _Float16* __restrict__ xh,
                                                 _Float16* __restrict__ xl,
                                                 _Float16* __restrict__ wh,
                                                 _Float16* __restrict__ wl,
                                                 const float* __restrict__ bout,
                                                 float* __restrict__ out) {
    __shared__ _Float16 lh[64 * 72];
    __shared__ _Float16 ll[64 * 72];
    const int tid = threadIdx.x;
    const int k0 = blockIdx.x * 64;

    if (blockIdx.x == 0 && blockIdx.y == 0 && tid < Bb) out[tid] = bout[0];

    const float* src;
    _Float16 *dh, *dl;
    int nrows, m0;
    if (blockIdx.y < 256) {
        src = x; dh = xh; dl = xl; nrows = Mm; m0 = blockIdx.y * 64;
    } else {
        src = Win; dh = wh; dl = wl; nrows = Hh; m0 = (blockIdx.y - 256) * 64;
    }

#pragma unroll
    for (int i = 0; i < 4; ++i) {
        const int lin = tid + i * 256;
        const int row = lin >> 4;
        const int c4 = (lin & 15) * 4;
        const float4 v = *(const float4*)(src + (size_t)(m0 + row) * Dd + k0 + c4);
        const float va[4] = {v.x, v.y, v.z, v.w};
        half4v h, l;
#pragma unroll
        for (int q = 0; q < 4; ++q) {
            const _Float16 hi = (_Float16)va[q];
            h[q] = hi;
            l[q] = (_Float16)((va[q] - (float)hi) * 4096.0f);
        }
        *(half4v*)&lh[row * 72 + c4] = h;
        *(half4v*)&ll[row * 72 + c4] = l;
    }
    __syncthreads();
#pragma unroll
    for (int i = 0; i < 2; ++i) {
        const int lin = tid + i * 256;
        const int kc = lin >> 6;   // 0..7
        const int mm = lin & 63;
        const half8 h = *(const half8*)&lh[mm * 72 + kc * 8];
        const half8 l = *(const half8*)&ll[mm * 72 + kc * 8];
        const size_t g = (size_t)(k0 / 8 + kc) * nrows + m0 + mm;
        *(half8*)(dh + g * 8) = h;
        *(half8*)(dl + g * 8) = l;
    }
}

// ---------------------------------------------------------------------------
// Kernel 2: FUSED MFMA GEMM + ALIF scan, BN=128 (R8).
// R8 theory: the 64us invariant across 7 schedule variants is L3/fabric BW.
// At BN=64, A is re-read by 16 blocks/batch: 512MB A + 128MB B = 640MB over
// 64.7us = 9.9 TB/s sustained from Infinity Cache (FETCH ~25MB = cold pass
// only). Fix is structural: BN 64->128 halves A re-reads (384MB total).
// Geometry: 512 threads / 8 waves (4M x 2N), per-wave output 64x64 (same
// 8x floatx16 acc = 128 AGPR, same 384 MFMA/wave), BK=32, 16 super-stages,
// qq in {0,1}. BM=256 fixed (serial T-scan forbids M-split). Grid 512.
// Kept: A direct global->reg 1-ahead (rot=hs&1), B-frag register dbuf
// (rot=qq), counted vmcnt(4) + raw s_barrier, 3-group MFMA order
// (bit-exact), setprio, bijective XCD swizzle (512%8==0).
// Epilogue: two ni-passes over [256][64] scanbuf (64KB, reuses B region);
// wave 0 scans 64 cols/pass with 16-deep load-ahead; one atomicAdd per blk.
// Occupancy: 8 waves x ~230 reg -> 8 waves/CU = 1 block/CU, 2 gens.
// ---------------------------------------------------------------------------
__global__ __launch_bounds__(512, 2) void gemm_fused(const _Float16* __restrict__ xh,
                                                     const _Float16* __restrict__ xl,
                                                     const _Float16* __restrict__ wh,
                                                     const _Float16* __restrict__ wl,
                                                     const float* __restrict__ bin,
                                                     const float* __restrict__ Wout,
                                                     float* __restrict__ out) {
    __shared__ float ldsS[16384];  // 64KB: K-loop uses first 32KB as B dbuf;
                                   // epilogue reuses all 64KB as [256][64] scanbuf.
    _Float16* ldsB = (_Float16*)ldsS;  // [buf][arr][4096 halves]

    const int tid = threadIdx.x;
    // XCD swizzle: j = id%8 = XCD slot; batch b ≡ j (mod 8); n-tile fast.
    const int id = blockIdx.x;          // 0..511
    const int j  = id & 7;
    const int q  = id >> 3;             // 0..63
    const int nt = q & 7;               // n-tile 0..7 (128 cols each)
    const int b  = (q >> 3) * 8 + j;    // batch 0..63
    const int m0 = b * Tt;              // = b*256
    const int n0 = nt * 128;

    const int lane = tid & 63;
    const int wave = tid >> 6;          // 0..7
    const int wm = wave >> 1;           // 0..3: rows [64*wm, 64*wm+64)
    const int wn = wave & 1;            // 0..1: cols [64*wn, 64*wn+64) of tile
    const int lr = lane & 31;
    const int lk = lane >> 5;

    floatx16 acc[2][2], accx[2][2];
#pragma unroll
    for (int mi = 0; mi < 2; ++mi)
#pragma unroll
        for (int ni = 0; ni < 2; ++ni)
#pragma unroll
            for (int r = 0; r < 16; ++r) { acc[mi][ni][r] = 0.0f; accx[mi][ni][r] = 0.0f; }

    // --- B staging: super-stage SS covers k-chunks [SS*4, SS*4+4) (32 k).
    // Per array: 4 chunks x 128 cols = 512 chunk-slots; 1 slot/thread.
#define STAGE_B(buf, SS)                                                             \
    do {                                                                             \
        const int kc_ = tid >> 7;                                                    \
        const int col_ = tid & 127;                                                  \
        const size_t g_ = ((size_t)((SS) * 4 + kc_) * Hh + n0 + col_) * 8;           \
        __builtin_amdgcn_global_load_lds(GPTR(wh + g_), LPTR(&ldsB[((buf) * 2 + 0) * 4096 + tid * 8]), 16, 0, 0); \
        __builtin_amdgcn_global_load_lds(GPTR(wl + g_), LPTR(&ldsB[((buf) * 2 + 1) * 4096 + tid * 8]), 16, 0, 0); \
    } while (0)

    // --- A direct loads (wave-private rows): half-stage hs, kc = hs*2 + lk ---
    const size_t arow0 = (size_t)(m0 + wm * 64 + lr);  // +32 for mi=1
    half8 ah[2][2], al[2][2];  // [rot][mi]; rot = hs & 1 (1-ahead)
#define LOAD_A(rot, hs)                                                              \
    do {                                                                             \
        const size_t kA = (size_t)((hs) * 2 + lk) * Mm;                              \
        ah[rot][0] = *(const half8*)(xh + (kA + arow0) * 8);                         \
        ah[rot][1] = *(const half8*)(xh + (kA + arow0 + 32) * 8);                    \
        al[rot][0] = *(const half8*)(xl + (kA + arow0) * 8);                         \
        al[rot][1] = *(const half8*)(xl + (kA + arow0 + 32) * 8);                    \
    } while (0)

    // --- B fragments, explicit 2-deep register double-buffer ---
    half8 bfh[2][2], bfl[2][2];  // [rot][ni]; rot = qq (compile-time)
#define LOAD_BF(rot_, qq_, cur_)                                                     \
    do {                                                                             \
        _Pragma("unroll")                                                            \
        for (int ni_ = 0; ni_ < 2; ++ni_) {                                          \
            const int ci_ = ((qq_) * 2 + lk) * 128 + wn * 64 + ni_ * 32 + lr;        \
            bfh[rot_][ni_] = *(const half8*)&ldsB[((cur_) * 2 + 0) * 4096 + ci_ * 8];\
            bfl[rot_][ni_] = *(const half8*)&ldsB[((cur_) * 2 + 1) * 4096 + ci_ * 8];\
        }                                                                            \
    } while (0)

#define SB0() __builtin_amdgcn_sched_barrier(0)
#define WAITVM4() asm volatile("s_waitcnt vmcnt(4)" ::: "memory")
#define CFENCE() asm volatile("" ::: "memory")

    // Prologue: stage B(0) (2 glds), prefetch A hs=0 (4 loads).
    // vmcnt(4) retires the 2 staging glds, keeps the 4 A-loads in flight.
    STAGE_B(0, 0);
    SB0();
    LOAD_A(0, 0);
    SB0();
    WAITVM4();
    __builtin_amdgcn_s_barrier();
    CFENCE();

    for (int SS = 0; SS < 16; ++SS) {
        if (SS < 15) { STAGE_B((SS + 1) & 1, SS + 1); SB0(); }
        const int cur = SS & 1;
        LOAD_BF(0, 0, cur);  // prime the B-fragment pipeline for qq=0
#pragma unroll
        for (int qq = 0; qq < 2; ++qq) {
            const int hs = SS * 2 + qq;
            const int arot = hs & 1;
            // Pipeline: next-qq B-frag ds_reads + next-hs A loads issue first;
            // their latencies hide under this qq's MFMAs.
            if (qq < 1) LOAD_BF(1, 1, cur);
            if (hs + 1 < 32) LOAD_A((hs + 1) & 1, hs + 1);

            // 3 groups of 4 independent accumulators (bit-exact per-acc order).
            __builtin_amdgcn_s_setprio(1);
#pragma unroll
            for (int mi = 0; mi < 2; ++mi)
#pragma unroll
                for (int ni = 0; ni < 2; ++ni)
                    acc[mi][ni]  = __builtin_amdgcn_mfma_f32_32x32x16_f16(ah[arot][mi], bfh[qq][ni], acc[mi][ni], 0, 0, 0);
#pragma unroll
            for (int mi = 0; mi < 2; ++mi)
#pragma unroll
                for (int ni = 0; ni < 2; ++ni)
                    accx[mi][ni] = __builtin_amdgcn_mfma_f32_32x32x16_f16(ah[arot][mi], bfl[qq][ni], accx[mi][ni], 0, 0, 0);
#pragma unroll
            for (int mi = 0; mi < 2; ++mi)
#pragma unroll
                for (int ni = 0; ni < 2; ++ni)
                    accx[mi][ni] = __builtin_amdgcn_mfma_f32_32x32x16_f16(al[arot][mi], bfh[qq][ni], accx[mi][ni], 0, 0, 0);
            __builtin_amdgcn_s_setprio(0);
        }
        if (SS < 15) {
            SB0();           // pin: staging glds(SS+1) issued before qq1's A-loads
            WAITVM4();       // retire 2 staging glds; keep the 4 newest A-loads flying
            __builtin_amdgcn_s_barrier();
            CFENCE();        // no LDS read hoists above the barrier
        }
    }
#undef STAGE_B
#undef LOAD_A
#undef LOAD_BF

    // ------------- fused ALIF scan epilogue (two ni-passes) -------------
    // Pass p covers cols {wn*64 + p*32 + lr}: 64 distinct h per pass.
    // scanbuf [256 t][64 c], c = wn*32 + lr. 64KB, reuses the whole LDS.
    float* scanbuf = ldsS;
    float val = 0.0f;  // lanes of wave 0 accumulate over passes

#pragma unroll
    for (int p = 0; p < 2; ++p) {
        __syncthreads();  // p0: K-loop LDS reads done; p1: scan of p0 done
        const float bv = bin[n0 + wn * 64 + p * 32 + lr];
        // C/D layout (32x32): col = lane&31, row = (r&3) + 8*(r>>2) + 4*lk
#pragma unroll
        for (int mi = 0; mi < 2; ++mi)
#pragma unroll
            for (int r = 0; r < 16; ++r) {
                const int row = (r & 3) + 8 * (r >> 2) + 4 * lk;
                const int t = wm * 64 + mi * 32 + row;   // m_local == timestep
                scanbuf[t * 64 + wn * 32 + lr] =
                    acc[mi][p][r] + accx[mi][p][r] * (1.0f / 4096.0f) + bv;
            }
        __syncthreads();

        // Wave 0: lane c scans column c (h = n0 + (c>>5)*64 + p*32 + (c&31)).
        // Stride 64 floats -> 2 lanes/bank (free). 16-deep load-ahead keeps
        // the serial recurrence chain-latency-bound.
        if (wave == 0) {
            const float* sb = scanbuf + lane;
            const float wout = Wout[n0 + (lane >> 5) * 64 + p * 32 + (lane & 31)];
            float mem = 0.0f, adapt = 0.0f, cnt = 0.0f;

            float buf[16];
#pragma unroll
            for (int jj = 0; jj < 16; ++jj) buf[jj] = sb[jj * 64];

            for (int t0 = 0; t0 < Tt; t0 += 16) {
                float cur[16];
#pragma unroll
                for (int jj = 0; jj < 16; ++jj) cur[jj] = buf[jj];
                if (t0 + 16 < Tt) {
#pragma unroll
                    for (int jj = 0; jj < 16; ++jj) buf[jj] = sb[(t0 + 16 + jj) * 64];
                }
#pragma unroll
                for (int jj = 0; jj < 16; ++jj) {
                    mem = 0.9f * mem + cur[jj] - adapt;
                    const float spk = (mem > 0.0f) ? 1.0f : 0.0f;
                    adapt += 0.1f * spk;
                    mem -= spk;
                    cnt += spk;
                }
            }
            val += cnt * wout * (1.0f / (float)Tt);
        }
    }

    if (wave == 0) {
#pragma unroll
        for (int off = 32; off > 0; off >>= 1) val += __shfl_down(val, off, 64);
        if (lane == 0) atomicAdd(&out[b], val);
    }
}

// ---------------------------------------------------------------------------
// Fallback fp32 SIMT GEMM + scan (proven) in case ws is too small.
// ---------------------------------------------------------------------------
#define BK 16
#define BMP 132
__global__ __launch_bounds__(256) void gemm_pre(const float* __restrict__ x,
                                                const float* __restrict__ Win,
                                                const float* __restrict__ bin,
                                                float* __restrict__ pre) {
    __shared__ float As[BK][BMP];
    __shared__ float Bs[BK][BMP];
    const int tid = threadIdx.x;
    const int m0 = blockIdx.y * 128;
    const int n0 = blockIdx.x * 128;
    const int tx = tid & 15;
    const int ty = tid >> 4;
    float acc[8][8];
#pragma unroll
    for (int i = 0; i < 8; ++i)
#pragma unroll
        for (int jj = 0; jj < 8; ++jj) acc[i][jj] = 0.0f;
    const float* Aptr = x + (size_t)m0 * Dd;
    const float* Bptr = Win + (size_t)n0 * Dd;
    for (int k0 = 0; k0 < Dd; k0 += BK) {
#pragma unroll
        for (int i = 0; i < 2; ++i) {
            const int lin = tid + i * 256;
            const int row = lin >> 2;
            const int kq = (lin & 3) << 2;
            const float4 av = *(const float4*)(Aptr + (size_t)row * Dd + k0 + kq);
            const float4 bv = *(const float4*)(Bptr + (size_t)row * Dd + k0 + kq);
            As[kq + 0][row] = av.x; As[kq + 1][row] = av.y;
            As[kq + 2][row] = av.z; As[kq + 3][row] = av.w;
            Bs[kq + 0][row] = bv.x; Bs[kq + 1][row] = bv.y;
            Bs[kq + 2][row] = bv.z; Bs[kq + 3][row] = bv.w;
        }
        __syncthreads();
#pragma unroll
        for (int kk = 0; kk < BK; ++kk) {
            const float4 a0 = *(const float4*)&As[kk][ty * 4];
            const float4 a1 = *(const float4*)&As[kk][ty * 4 + 64];
            const float4 b0 = *(const float4*)&Bs[kk][tx * 4];
            const float4 b1 = *(const float4*)&Bs[kk][tx * 4 + 64];
            const float a[8] = {a0.x, a0.y, a0.z, a0.w, a1.x, a1.y, a1.z, a1.w};
            const float b[8] = {b0.x, b0.y, b0.z, b0.w, b1.x, b1.y, b1.z, b1.w};
#pragma unroll
            for (int i = 0; i < 8; ++i)
#pragma unroll
                for (int jj = 0; jj < 8; ++jj) acc[i][jj] += a[i] * b[jj];
        }
        __syncthreads();
    }
#pragma unroll
    for (int i = 0; i < 8; ++i) {
        const int m = m0 + ((i < 4) ? (ty * 4 + i) : (64 + ty * 4 + i - 4));
#pragma unroll
        for (int half = 0; half < 2; ++half) {
            const int n = n0 + tx * 4 + half * 64;
            float4 v;
            v.x = acc[i][half * 4 + 0] + bin[n + 0];
            v.y = acc[i][half * 4 + 1] + bin[n + 1];
            v.z = acc[i][half * 4 + 2] + bin[n + 2];
            v.w = acc[i][half * 4 + 3] + bin[n + 3];
            *(float4*)(pre + (size_t)m * Hh + n) = v;
        }
    }
}

__global__ __launch_bounds__(64) void init_out(const float* __restrict__ bout,
                                               float* __restrict__ out) {
    out[threadIdx.x] = bout[0];
}

__global__ __launch_bounds__(64) void alif_scan(const float* __restrict__ pre,
                                                const float* __restrict__ Wout,
                                                float* __restrict__ out) {
    const int h = blockIdx.x * 64 + threadIdx.x;
    const int b = blockIdx.y;
    const float* p = pre + (size_t)b * Tt * Hh + h;

    float buf[32];
#pragma unroll
    for (int jj = 0; jj < 32; ++jj) buf[jj] = p[(size_t)jj * Hh];

    float mem = 0.0f, adapt = 0.0f, cnt = 0.0f;
    for (int t0 = 0; t0 < Tt; t0 += 32) {
        float cur[32];
#pragma unroll
        for (int jj = 0; jj < 32; ++jj) cur[jj] = buf[jj];
        if (t0 + 32 < Tt) {
#pragma unroll
            for (int jj = 0; jj < 32; ++jj) buf[jj] = p[(size_t)(t0 + 32 + jj) * Hh];
        }
#pragma unroll
        for (int jj = 0; jj < 32; ++jj) {
            mem = 0.9f * mem + cur[jj] - adapt;
            const float spk = (mem > 0.0f) ? 1.0f : 0.0f;
            adapt += 0.1f * spk;
            mem -= spk;
            cnt += spk;
        }
    }

    float val = cnt * Wout[h] * (1.0f / (float)Tt);
#pragma unroll
    for (int off = 32; off > 0; off >>= 1) val += __shfl_down(val, off, 64);
    if (threadIdx.x == 0) atomicAdd(&out[b], val);
}

extern "C" void kernel_launch(void* const* d_in, const int* in_sizes, int n_in,
                              void* d_out, int out_size, void* d_ws, size_t ws_size,
                              hipStream_t stream) {
    const float* x    = (const float*)d_in[0];
    const float* Win  = (const float*)d_in[1];
    const float* bin  = (const float*)d_in[2];
    const float* Wout = (const float*)d_in[3];
    const float* bout = (const float*)d_in[4];
    float* out = (float*)d_out;

    const size_t xh_bytes = (size_t)Mm * Dd * 2;   // 16 MiB
    const size_t wh_bytes = (size_t)Hh * Dd * 2;   // 1 MiB
    const size_t need = 2 * xh_bytes + 2 * wh_bytes + 4096;

    if (ws_size >= need) {
        char* base = (char*)d_ws;
        _Float16* xh = (_Float16*)base;
        _Float16* xl = (_Float16*)(base + xh_bytes);
        _Float16* wh = (_Float16*)(base + 2 * xh_bytes);
        _Float16* wl = (_Float16*)(base + 2 * xh_bytes + wh_bytes);

        // x: 256 row-tiles of 64; W: 16 row-tiles of 64. 8 k-tiles of 64.
        convert_t<<<dim3(8, 272), 256, 0, stream>>>(x, Win, xh, xl, wh, wl, bout, out);

        // 512 blocks of 512 threads: 64 batches x 8 n-tiles (BN=128).
        gemm_fused<<<512, 512, 0, stream>>>(xh, xl, wh, wl, bin, Wout, out);
    } else {
        float* pre = (float*)d_ws;  // needs 64 MiB
        init_out<<<1, 64, 0, stream>>>(bout, out);
        dim3 g1(Hh / 128, Mm / 128);
        gemm_pre<<<g1, 256, 0, stream>>>(x, Win, bin, pre);
        alif_scan<<<dim3(Hh / 64, Bb), 64, 0, stream>>>(pre, Wout, out);
    }
}

// Round 9
// 142.641 us; speedup vs baseline: 1.1005x; 1.0937x over previous
//
#include <hip/hip_runtime.h>

// Problem dims
constexpr int Bb = 64;     // batch
constexpr int Tt = 256;    // timesteps
constexpr int Dd = 512;    // input dim (K)
constexpr int Hh = 1024;   // hidden (N)
constexpr int Mm = Bb * Tt;  // 16384 GEMM rows

typedef _Float16 half8 __attribute__((ext_vector_type(8)));
typedef _Float16 half4v __attribute__((ext_vector_type(4)));
typedef float floatx16 __attribute__((ext_vector_type(16)));

#define GPTR(x) ((const __attribute__((address_space(1))) void*)(x))
#define LPTR(x) ((__attribute__((address_space(3))) void*)(x))

// ---------------------------------------------------------------------------
// SESSION CONCLUSION (R9 revert-to-best):
// gemm_fused executes 51.5 GFLOP of f16 MFMA (3-pass hi/lo split, needed for
// bit-exact spike thresholds) in ~64 us = ~796 TF = 32% dense peak -- ABOVE
// the measured 607 TF reference for this 2-barrier K-loop structure class
// and ~87% of its ~900 TF ceiling (learn_hip m97/m131-141/m233). Verified
// null in this session: counted-vmcnt schedules (R1/R2), deeper A-prefetch
// (R4), B-frag register dbuf (R5), fused fp32-split (R6/R7: VALU-bound,
// issue 400cy vs 192cy MFMA per SIMD per hs), occupancy forcing (R3: spill
// disaster -- 128 AGPR acc + ~104 VGPR caps at 2 waves/SIMD), BN=128/8-wave
// (R8: -36%, refutes L3-BW theory). The >900 TF path (256sq 8-phase combo)
// needs 2x the register budget the split-GEMM permits and nulls at 128sq
// scale (m232). convert_t runs at ~80% of its 100MB traffic floor; fixed
// harness overhead ~60us. Addressable headroom ~10us/143 (~7%), all levers
// documented-null or precision-gated => this configuration is the keeper.
// ---------------------------------------------------------------------------

// ---------------------------------------------------------------------------
// Kernel 1: fp32 -> f16 hi/lo split, chunk-transposed.
// Output chunk g = kc*nrows + row holds src[row][kc*8..+8) as 8 halves, so
// GEMM A-fragment direct loads and B glds staging are coalesced.
// Also initializes out[b] = b_out (out is re-poisoned before every launch).
// ---------------------------------------------------------------------------
__global__ __launch_bounds__(256) void convert_t(const float* __restrict__ x,
                                                 const float* __restrict__ Win,
                                                 _Float16* __restrict__ xh,
                                                 _Float16* __restrict__ xl,
                                                 _Float16* __restrict__ wh,
                                                 _Float16* __restrict__ wl,
                                                 const float* __restrict__ bout,
                                                 float* __restrict__ out) {
    __shared__ _Float16 lh[64 * 72];
    __shared__ _Float16 ll[64 * 72];
    const int tid = threadIdx.x;
    const int k0 = blockIdx.x * 64;

    if (blockIdx.x == 0 && blockIdx.y == 0 && tid < Bb) out[tid] = bout[0];

    const float* src;
    _Float16 *dh, *dl;
    int nrows, m0;
    if (blockIdx.y < 256) {
        src = x; dh = xh; dl = xl; nrows = Mm; m0 = blockIdx.y * 64;
    } else {
        src = Win; dh = wh; dl = wl; nrows = Hh; m0 = (blockIdx.y - 256) * 64;
    }

#pragma unroll
    for (int i = 0; i < 4; ++i) {
        const int lin = tid + i * 256;
        const int row = lin >> 4;
        const int c4 = (lin & 15) * 4;
        const float4 v = *(const float4*)(src + (size_t)(m0 + row) * Dd + k0 + c4);
        const float va[4] = {v.x, v.y, v.z, v.w};
        half4v h, l;
#pragma unroll
        for (int q = 0; q < 4; ++q) {
            const _Float16 hi = (_Float16)va[q];
            h[q] = hi;
            l[q] = (_Float16)((va[q] - (float)hi) * 4096.0f);
        }
        *(half4v*)&lh[row * 72 + c4] = h;
        *(half4v*)&ll[row * 72 + c4] = l;
    }
    __syncthreads();
#pragma unroll
    for (int i = 0; i < 2; ++i) {
        const int lin = tid + i * 256;
        const int kc = lin >> 6;   // 0..7
        const int mm = lin & 63;
        const half8 h = *(const half8*)&lh[mm * 72 + kc * 8];
        const half8 l = *(const half8*)&ll[mm * 72 + kc * 8];
        const size_t g = (size_t)(k0 / 8 + kc) * nrows + m0 + mm;
        *(half8*)(dh + g * 8) = h;
        *(half8*)(dl + g * 8) = l;
    }
}

// ---------------------------------------------------------------------------
// Kernel 2: FUSED MFMA GEMM + ALIF scan (proven-best configuration).
//  - A (xh/xl): wave-private rows -> DIRECT global->register, 1-ahead rotating
//    prefetch (zero redundancy, no LDS, no barriers for A).
//  - B (wh/wl): shared by all 4 waves -> global_load_lds into 32KB double-
//    buffered LDS, BK=64 super-stages (8 barriers total), conflict-free
//    16B-stride ds_read_b128 fragment reads (SQ_LDS_BANK_CONFLICT == 0).
// Tile M=256 (one batch b) x N=64, 4 waves. Epilogue: dump C into two
// stride-32 LDS scan buffers (full 64KB reused), wave 0 scans 64 h, one
// atomicAdd into out[b]. XCD swizzle: 16 n-blocks of one batch on one XCD.
// Occupancy: reg-capped at 2 waves/SIMD (128 AGPR acc + ~104 VGPR); R3
// proved forcing more spills catastrophically.
// ---------------------------------------------------------------------------
__global__ __launch_bounds__(256, 2) void gemm_fused(const _Float16* __restrict__ xh,
                                                     const _Float16* __restrict__ xl,
                                                     const _Float16* __restrict__ wh,
                                                     const _Float16* __restrict__ wl,
                                                     const float* __restrict__ bin,
                                                     const float* __restrict__ Wout,
                                                     float* __restrict__ out) {
    __shared__ float ldsS[16384];  // 64KB: K-loop uses first 32KB as B dbuf;
                                   // epilogue reuses all 64KB as scanbuf.
    _Float16* ldsB = (_Float16*)ldsS;  // [buf][arr][4096 halves]

    const int tid = threadIdx.x;
    // XCD swizzle: j = id%8 = XCD slot; batch b ≡ j (mod 8); n-tile fast.
    const int id = blockIdx.x;          // 0..1023
    const int j  = id & 7;
    const int q  = id >> 3;             // 0..127
    const int nt = q & 15;              // n-tile 0..15 (64 cols each)
    const int b  = (q >> 4) * 8 + j;    // batch 0..63
    const int m0 = b * Tt;              // = b*256
    const int n0 = nt * 64;

    const int lane = tid & 63;
    const int wave = tid >> 6;          // 0..3, owns rows [64w, 64w+64)
    const int lr = lane & 31;
    const int lk = lane >> 5;

    floatx16 acc[2][2], accx[2][2];
#pragma unroll
    for (int mi = 0; mi < 2; ++mi)
#pragma unroll
        for (int ni = 0; ni < 2; ++ni)
#pragma unroll
            for (int r = 0; r < 16; ++r) { acc[mi][ni][r] = 0.0f; accx[mi][ni][r] = 0.0f; }

    // --- B staging: super-stage SS covers k-chunks [SS*8, SS*8+8) (64 k).
#define STAGE_B(buf, SS)                                                             \
    do {                                                                             \
        _Pragma("unroll")                                                            \
        for (int i_ = 0; i_ < 2; ++i_) {                                             \
            const int c_ = tid + i_ * 256;                                           \
            const int kc_ = c_ >> 6;                                                 \
            const int col_ = c_ & 63;                                                \
            const size_t g_ = ((size_t)((SS) * 8 + kc_) * Hh + n0 + col_) * 8;       \
            __builtin_amdgcn_global_load_lds(GPTR(wh + g_), LPTR(&ldsB[((buf) * 2 + 0) * 4096 + c_ * 8]), 16, 0, 0); \
            __builtin_amdgcn_global_load_lds(GPTR(wl + g_), LPTR(&ldsB[((buf) * 2 + 1) * 4096 + c_ * 8]), 16, 0, 0); \
        }                                                                            \
    } while (0)

    // --- A direct loads (wave-private rows): half-stage hs, kc = hs*2 + lk ---
    const size_t arow0 = (size_t)(m0 + wave * 64 + lr);  // +32 for mi=1
    half8 aset[2][4];  // [rot][ah0, ah1, al0, al1]
#define LOAD_A(rot, hs)                                                              \
    do {                                                                             \
        const size_t kA = (size_t)((hs) * 2 + lk) * Mm;                              \
        aset[rot][0] = *(const half8*)(xh + (kA + arow0) * 8);                       \
        aset[rot][1] = *(const half8*)(xh + (kA + arow0 + 32) * 8);                  \
        aset[rot][2] = *(const half8*)(xl + (kA + arow0) * 8);                       \
        aset[rot][3] = *(const half8*)(xl + (kA + arow0 + 32) * 8);                  \
    } while (0)

    STAGE_B(0, 0);
    LOAD_A(0, 0);

    for (int SS = 0; SS < 8; ++SS) {
        __syncthreads();  // B(SS) staged; other buf safe to overwrite
        if (SS < 7) STAGE_B((SS + 1) & 1, SS + 1);
        const int cur = SS & 1;
#pragma unroll
        for (int qq = 0; qq < 4; ++qq) {
            const int hs = SS * 4 + qq;
            const int rot = hs & 1;
            if (hs < 31) LOAD_A(rot ^ 1, hs + 1);

            // B fragments from LDS: kc_local = qq*2 + lk, col = ni*32 + lr
            half8 bh[2], bl[2];
#pragma unroll
            for (int ni = 0; ni < 2; ++ni) {
                const int ci = (qq * 2 + lk) * 64 + ni * 32 + lr;
                bh[ni] = *(const half8*)&ldsB[(cur * 2 + 0) * 4096 + ci * 8];
                bl[ni] = *(const half8*)&ldsB[(cur * 2 + 1) * 4096 + ci * 8];
            }
#pragma unroll
            for (int mi = 0; mi < 2; ++mi)
#pragma unroll
                for (int ni = 0; ni < 2; ++ni) {
                    acc[mi][ni]  = __builtin_amdgcn_mfma_f32_32x32x16_f16(aset[rot][mi],     bh[ni], acc[mi][ni], 0, 0, 0);
                    accx[mi][ni] = __builtin_amdgcn_mfma_f32_32x32x16_f16(aset[rot][mi],     bl[ni], accx[mi][ni], 0, 0, 0);
                    accx[mi][ni] = __builtin_amdgcn_mfma_f32_32x32x16_f16(aset[rot][2 + mi], bh[ni], accx[mi][ni], 0, 0, 0);
                }
        }
    }
#undef STAGE_B
#undef LOAD_A

    // ---------------- fused ALIF scan epilogue ----------------
    __syncthreads();  // all K-loop LDS reads done; reuse ldsS as 2 scan buffers
    float* scanbuf = ldsS;  // buffer p at offset p*8192 floats (stride 32)

#pragma unroll
    for (int p = 0; p < 2; ++p) {
        const float bv = bin[n0 + p * 32 + lr];
        // C/D layout (32x32): col = lane&31, row = (r&3) + 8*(r>>2) + 4*lk
#pragma unroll
        for (int mi = 0; mi < 2; ++mi)
#pragma unroll
            for (int r = 0; r < 16; ++r) {
                const int row = (r & 3) + 8 * (r >> 2) + 4 * lk;
                const int t = wave * 64 + mi * 32 + row;   // m_local == timestep
                scanbuf[p * 8192 + t * 32 + lr] =
                    acc[mi][p][r] + accx[mi][p][r] * (1.0f / 4096.0f) + bv;
            }
    }
    __syncthreads();

    // Wave 0 scans all 64 h (lane = h - n0); waves 1-3 exit immediately.
    if (wave == 0) {
        const float* sb = scanbuf + (lane >> 5) * 8192 + (lane & 31);
        float mem = 0.0f, adapt = 0.0f, cnt = 0.0f;
#pragma unroll 8
        for (int t = 0; t < Tt; ++t) {
            const float v = sb[t * 32];
            mem = 0.9f * mem + v - adapt;
            const float spk = (mem > 0.0f) ? 1.0f : 0.0f;
            adapt += 0.1f * spk;
            mem -= spk;
            cnt += spk;
        }
        float val = cnt * Wout[n0 + lane] * (1.0f / (float)Tt);
#pragma unroll
        for (int off = 32; off > 0; off >>= 1) val += __shfl_down(val, off, 64);
        if (lane == 0) atomicAdd(&out[b], val);
    }
}

// ---------------------------------------------------------------------------
// Fallback fp32 SIMT GEMM + scan (proven) in case ws is too small.
// ---------------------------------------------------------------------------
#define BK 16
#define BMP 132
__global__ __launch_bounds__(256) void gemm_pre(const float* __restrict__ x,
                                                const float* __restrict__ Win,
                                                const float* __restrict__ bin,
                                                float* __restrict__ pre) {
    __shared__ float As[BK][BMP];
    __shared__ float Bs[BK][BMP];
    const int tid = threadIdx.x;
    const int m0 = blockIdx.y * 128;
    const int n0 = blockIdx.x * 128;
    const int tx = tid & 15;
    const int ty = tid >> 4;
    float acc[8][8];
#pragma unroll
    for (int i = 0; i < 8; ++i)
#pragma unroll
        for (int jj = 0; jj < 8; ++jj) acc[i][jj] = 0.0f;
    const float* Aptr = x + (size_t)m0 * Dd;
    const float* Bptr = Win + (size_t)n0 * Dd;
    for (int k0 = 0; k0 < Dd; k0 += BK) {
#pragma unroll
        for (int i = 0; i < 2; ++i) {
            const int lin = tid + i * 256;
            const int row = lin >> 2;
            const int kq = (lin & 3) << 2;
            const float4 av = *(const float4*)(Aptr + (size_t)row * Dd + k0 + kq);
            const float4 bv = *(const float4*)(Bptr + (size_t)row * Dd + k0 + kq);
            As[kq + 0][row] = av.x; As[kq + 1][row] = av.y;
            As[kq + 2][row] = av.z; As[kq + 3][row] = av.w;
            Bs[kq + 0][row] = bv.x; Bs[kq + 1][row] = bv.y;
            Bs[kq + 2][row] = bv.z; Bs[kq + 3][row] = bv.w;
        }
        __syncthreads();
#pragma unroll
        for (int kk = 0; kk < BK; ++kk) {
            const float4 a0 = *(const float4*)&As[kk][ty * 4];
            const float4 a1 = *(const float4*)&As[kk][ty * 4 + 64];
            const float4 b0 = *(const float4*)&Bs[kk][tx * 4];
            const float4 b1 = *(const float4*)&Bs[kk][tx * 4 + 64];
            const float a[8] = {a0.x, a0.y, a0.z, a0.w, a1.x, a1.y, a1.z, a1.w};
            const float b[8] = {b0.x, b0.y, b0.z, b0.w, b1.x, b1.y, b1.z, b1.w};
#pragma unroll
            for (int i = 0; i < 8; ++i)
#pragma unroll
                for (int jj = 0; jj < 8; ++jj) acc[i][jj] += a[i] * b[jj];
        }
        __syncthreads();
    }
#pragma unroll
    for (int i = 0; i < 8; ++i) {
        const int m = m0 + ((i < 4) ? (ty * 4 + i) : (64 + ty * 4 + i - 4));
#pragma unroll
        for (int half = 0; half < 2; ++half) {
            const int n = n0 + tx * 4 + half * 64;
            float4 v;
            v.x = acc[i][half * 4 + 0] + bin[n + 0];
            v.y = acc[i][half * 4 + 1] + bin[n + 1];
            v.z = acc[i][half * 4 + 2] + bin[n + 2];
            v.w = acc[i][half * 4 + 3] + bin[n + 3];
            *(float4*)(pre + (size_t)m * Hh + n) = v;
        }
    }
}

__global__ __launch_bounds__(64) void init_out(const float* __restrict__ bout,
                                               float* __restrict__ out) {
    out[threadIdx.x] = bout[0];
}

__global__ __launch_bounds__(64) void alif_scan(const float* __restrict__ pre,
                                                const float* __restrict__ Wout,
                                                float* __restrict__ out) {
    const int h = blockIdx.x * 64 + threadIdx.x;
    const int b = blockIdx.y;
    const float* p = pre + (size_t)b * Tt * Hh + h;

    float buf[32];
#pragma unroll
    for (int jj = 0; jj < 32; ++jj) buf[jj] = p[(size_t)jj * Hh];

    float mem = 0.0f, adapt = 0.0f, cnt = 0.0f;
    for (int t0 = 0; t0 < Tt; t0 += 32) {
        float cur[32];
#pragma unroll
        for (int jj = 0; jj < 32; ++jj) cur[jj] = buf[jj];
        if (t0 + 32 < Tt) {
#pragma unroll
            for (int jj = 0; jj < 32; ++jj) buf[jj] = p[(size_t)(t0 + 32 + jj) * Hh];
        }
#pragma unroll
        for (int jj = 0; jj < 32; ++jj) {
            mem = 0.9f * mem + cur[jj] - adapt;
            const float spk = (mem > 0.0f) ? 1.0f : 0.0f;
            adapt += 0.1f * spk;
            mem -= spk;
            cnt += spk;
        }
    }

    float val = cnt * Wout[h] * (1.0f / (float)Tt);
#pragma unroll
    for (int off = 32; off > 0; off >>= 1) val += __shfl_down(val, off, 64);
    if (threadIdx.x == 0) atomicAdd(&out[b], val);
}

extern "C" void kernel_launch(void* const* d_in, const int* in_sizes, int n_in,
                              void* d_out, int out_size, void* d_ws, size_t ws_size,
                              hipStream_t stream) {
    const float* x    = (const float*)d_in[0];
    const float* Win  = (const float*)d_in[1];
    const float* bin  = (const float*)d_in[2];
    const float* Wout = (const float*)d_in[3];
    const float* bout = (const float*)d_in[4];
    float* out = (float*)d_out;

    const size_t xh_bytes = (size_t)Mm * Dd * 2;   // 16 MiB
    const size_t wh_bytes = (size_t)Hh * Dd * 2;   // 1 MiB
    const size_t need = 2 * xh_bytes + 2 * wh_bytes + 4096;

    if (ws_size >= need) {
        char* base = (char*)d_ws;
        _Float16* xh = (_Float16*)base;
        _Float16* xl = (_Float16*)(base + xh_bytes);
        _Float16* wh = (_Float16*)(base + 2 * xh_bytes);
        _Float16* wl = (_Float16*)(base + 2 * xh_bytes + wh_bytes);

        // x: 256 row-tiles of 64; W: 16 row-tiles of 64. 8 k-tiles of 64.
        convert_t<<<dim3(8, 272), 256, 0, stream>>>(x, Win, xh, xl, wh, wl, bout, out);

        gemm_fused<<<1024, 256, 0, stream>>>(xh, xl, wh, wl, bin, Wout, out);
    } else {
        float* pre = (float*)d_ws;  // needs 64 MiB
        init_out<<<1, 64, 0, stream>>>(bout, out);
        dim3 g1(Hh / 128, Mm / 128);
        gemm_pre<<<g1, 256, 0, stream>>>(x, Win, bin, pre);
        alif_scan<<<dim3(Hh / 64, Bb), 64, 0, stream>>>(pre, Wout, out);
    }
}